// Round 1
// 842.350 us; speedup vs baseline: 1.0570x; 1.0570x over previous
//
#include <hip/hip_runtime.h>

#define MAX_VAL 10000.0f

// x: (B=8, C=64, H=512, W=512) float32, row-major.
// Output: erode(3x3 min) on channels in `indices`, copy otherwise (k==3 baked).
//
// Strip decomposition: each thread owns 4 consecutive columns x 8 consecutive
// rows of one plane. Vertical 3-row min is kept as a rolling window of
// per-row HORIZONTAL mins in registers, so each input row is loaded once per
// thread: 10 row-loads per 8 output rows (1.25x) instead of 3x, and the reuse
// is in registers (immune to round-robin block->XCD dispatch killing L2
// vertical locality).
//
// Block = 256 threads = full row width (128 float4 lanes) x 2 strips.
// Strips 2k and 2k+1 always share a plane (64 strips/plane, even start), so
// the erode/copy branch is block-uniform.
__global__ __launch_bounds__(256) void erode_kernel(
    const float* __restrict__ x,
    const int* __restrict__ indices, int n_idx,
    float* __restrict__ out)
{
    const unsigned tid   = threadIdx.x;
    const unsigned w4    = tid & 127u;            // float4-group within row
    const unsigned S     = blockIdx.x * 2u + (tid >> 7);  // global strip id
    const unsigned bc    = S >> 6;                // plane index (b*64 + c)
    const unsigned strip = S & 63u;               // strip within plane
    const unsigned h0    = strip * 8u;            // first output row
    const unsigned c     = bc & 63u;
    const unsigned w0    = w4 * 4u;

    // Block-uniform channel membership, parallel scan (no serial 32-iter loop).
    __shared__ int s_flag;
    if (tid == 0) s_flag = 0;
    __syncthreads();
    for (unsigned i = tid; i < (unsigned)n_idx; i += 256u)
        if (indices[i] == (int)c) s_flag = 1;     // benign race, same value
    __syncthreads();

    const float* plane  = x   + (size_t)bc * (512u * 512u);
    float*       oplane = out + (size_t)bc * (512u * 512u);
    const float* ip = plane  + (size_t)h0 * 512u + w0;
    float*       op = oplane + (size_t)h0 * 512u + w0;

    if (!s_flag) {
        // Pass-through: streaming copy of 8 rows, fully coalesced.
#pragma unroll
        for (int r = 0; r < 8; ++r)
            *(float4*)(op + r * 512) = *(const float4*)(ip + r * 512);
        return;
    }

    const bool has_l = (w0 > 0);
    const bool has_r = (w0 + 4u < 512u);

    // Horizontal 3-min of row hh over this thread's 4 columns.
    // Halo scalars come from the same cache lines neighboring lanes load -> L1 hits.
    auto hrow = [&](int hh) -> float4 {
        float4 h;
        if (hh < 0 || hh > 511) {
            h.x = h.y = h.z = h.w = MAX_VAL;
            return h;
        }
        const float* row = plane + (size_t)hh * 512u;
        float4 v = *(const float4*)(row + w0);
        float ll = has_l ? row[w0 - 1] : MAX_VAL;
        float rr = has_r ? row[w0 + 4] : MAX_VAL;
        h.x = fminf(ll,  fminf(v.x, v.y));
        h.y = fminf(v.x, fminf(v.y, v.z));
        h.z = fminf(v.y, fminf(v.z, v.w));
        h.w = fminf(v.z, fminf(v.w, rr));
        return h;
    };

    // Rolling 3-row window of horizontal mins.
    float4 a = hrow((int)h0 - 1);
    float4 b = hrow((int)h0);
#pragma unroll
    for (int r = 0; r < 8; ++r) {
        float4 d = hrow((int)h0 + r + 1);
        float4 o;
        o.x = fminf(a.x, fminf(b.x, d.x));
        o.y = fminf(a.y, fminf(b.y, d.y));
        o.z = fminf(a.z, fminf(b.z, d.z));
        o.w = fminf(a.w, fminf(b.w, d.w));
        *(float4*)(op + r * 512) = o;
        a = b; b = d;
    }
}

extern "C" void kernel_launch(void* const* d_in, const int* in_sizes, int n_in,
                              void* d_out, int out_size, void* d_ws, size_t ws_size,
                              hipStream_t stream) {
    const float* x       = (const float*)d_in[0];
    const int*   indices = (const int*)d_in[1];
    // d_in[2] is k (==3), baked into the kernel.
    int n_idx = in_sizes[1];
    float* out = (float*)d_out;

    // Strips: 512 planes * (512 rows / 8 rows-per-strip) = 32768; 2 per block.
    dim3 grid(16384), block(256);
    erode_kernel<<<grid, block, 0, stream>>>(x, indices, n_idx, out);
}